// Round 1
// 88.562 us; speedup vs baseline: 1.0005x; 1.0005x over previous
//
#include <hip/hip_runtime.h>

#define BATCH 32
#define NROI  2000
#define NGT   100
#define NLBL  21
#define NPOS  64

// native vector type for nontemporal stores (clang builtin rejects HIP float4)
typedef float nfloat4 __attribute__((ext_vector_type(4)));

__device__ __forceinline__ void nt_store(const float4& v, float4* p) {
  nfloat4 nv = {v.x, v.y, v.z, v.w};
  __builtin_nontemporal_store(nv, (nfloat4*)p);
}

// ---------------------------------------------------------------------------
// R7: same 3-dispatch skeleton as R3/R6 (88.3-88.6 us, absmax 0.0), with the
// controllable time attacked on theory:
//  (a) K2 radix pass 0: digit = float bits[31:24] of max-IoU = sign+exp[7:1],
//      only ~4 distinct values -> ~2000 LDS atomicAdds into ~4 bins was a
//      ~500-way same-address serialization on just 32 blocks. Replaced with
//      wave-aggregated ballot counting (1 atomic per distinct digit per wave).
//  (b) delta math + argmax-label gather moved from K3 into K1 (whose threads
//      already do 100 IEEE divides; +2 div +2 log is noise). K2 now emits only
//      a 4B packed class code pc = pos ? gtlab+1 : 0 per roi; K3 is a pure
//      streaming writer (no egt/roi re-reads, no FP math, no maxidx array).
// Selection stays bit-exact: _rn IoU ops, composite key, radix order are
// unchanged -> absmax 0.0 preserved (selection flips are the only failure
// mode; delta-value contraction differences are absorbed by the 0.02 tol).
// Journal recap: R4 cooperative grid.sync ~175 us/sync (kernel 370 us);
// R5 spin-fusion +8 us vs an extra dispatch; batch-per-block fusion ~23 us
// by issue-port arithmetic. 3 dispatches + ~3 us gaps remain the floor.
// ---------------------------------------------------------------------------

// K1: per (b, roi): max/argmax IoU over 100 gt (strict > = first-max, matching
// jnp.argmax) + composite rank key + unconditional delta vs the argmax gt +
// that gt's label. Key = (float_bits(max_iou) << 16) | (0xFFFF - roi);
// iou >= 0 so float bits are order-monotonic; lower roi wins ties (stable
// descending argsort). _rn intrinsics forbid FMA contraction so the rounded
// IoU quotients bit-match the numpy reference.
__global__ __launch_bounds__(256) void iou_max_kernel(
    const float4* __restrict__ roi, const float4* __restrict__ gt,
    const int* __restrict__ gtlab, unsigned long long* __restrict__ keys,
    float4* __restrict__ delta, int* __restrict__ klab) {
  __shared__ float4 sgt[NGT];
  __shared__ float sga[NGT];
  __shared__ int sgl[NGT];
  const int b = blockIdx.y;
  const int r = blockIdx.x * 256 + threadIdx.x;
  if (threadIdx.x < NGT) {
    float4 g = gt[b * NGT + threadIdx.x];
    sgt[threadIdx.x] = g;
    sga[threadIdx.x] = __fmul_rn(__fsub_rn(g.z, g.x), __fsub_rn(g.w, g.y));
    sgl[threadIdx.x] = gtlab[b * NGT + threadIdx.x];
  }
  __syncthreads();
  if (r >= NROI) return;
  // box layout [y1,x1,y2,x2]: .x=y1 .y=x1 .z=y2 .w=x2
  float4 rb = roi[b * NROI + r];
  float bb_area = __fmul_rn(__fsub_rn(rb.z, rb.x), __fsub_rn(rb.w, rb.y));
  float best = -1.0f;
  int bi = 0;
#pragma unroll 4
  for (int m = 0; m < NGT; ++m) {
    float4 g = sgt[m];
    float xt = fmaxf(rb.y, g.y);
    float yt = fmaxf(rb.x, g.x);
    float xb = fminf(rb.w, g.w);
    float yb = fminf(rb.z, g.z);
    float iw = fmaxf(__fsub_rn(xb, xt), 0.0f);
    float ih = fmaxf(__fsub_rn(yb, yt), 0.0f);
    float inter = __fmul_rn(iw, ih);
    float uni = __fsub_rn(__fadd_rn(bb_area, sga[m]), inter);  // left-to-right like np
    float iou = __fdiv_rn(inter, uni);
    if (iou > best) { best = iou; bi = m; }
  }
  const int ridx = b * NROI + r;
  unsigned int fb = __float_as_uint(best);
  keys[ridx] =
      ((unsigned long long)fb << 16) | (unsigned long long)(0xFFFFu - (unsigned)r);
  // delta vs argmax gt, ungated (K3 gates by pos && class). gt boxes have
  // wh >= 0.01 so gw,gh > 0 for every real gt; guards kept for parity.
  float4 g = sgt[bi];
  float bw = rb.w - rb.y, bh = rb.z - rb.x;
  float bcx = rb.y + 0.5f * bw, bcy = rb.x + 0.5f * bh;
  float gw = g.w - g.y, gh = g.z - g.x;
  float gcx = g.y + 0.5f * gw, gcy = g.x + 0.5f * gh;
  if (bw == 0.f) bw = 1e-3f;
  if (bh == 0.f) bh = 1e-3f;
  float dx  = (gw == 0.f) ? 0.f : (gcx - bcx) / bw;
  float dy  = (gh == 0.f) ? 0.f : (gcy - bcy) / bh;
  float dwv = (gw == 0.f) ? 0.f : logf(gw / bw);
  float dhv = (gh == 0.f) ? 0.f : logf(gh / bh);
  delta[ridx] = make_float4(dy, dx, dhv, dwv);  // [dy, dx, dh, dw]
  klab[ridx] = sgl[bi];
}

// K2: one block per batch. Radix-select the 64th-largest key (MSB-first,
// 8-bit digits, 6 passes; keys < 2^46). Keys live in registers (8/thread).
// Pass 0 uses wave-aggregated ballot counting (digits concentrated in ~4
// exponent bins -> plain atomics serialize ~500-way); later passes use plain
// LDS atomics (digits spread / candidate set small). Keys are distinct so
// pos <=> key >= K64. Output: pc[ridx] = pos ? gtlab[argmax]+1 : 0.
__global__ __launch_bounds__(256) void select_kernel(
    const unsigned long long* __restrict__ keys, const int* __restrict__ klab,
    int* __restrict__ pc) {
  const int b = blockIdx.x;
  const int t = threadIdx.x;
  unsigned long long k[8];
#pragma unroll
  for (int j = 0; j < 8; ++j) {
    int i = t + j * 256;
    k[j] = (i < NROI) ? keys[b * NROI + i] : 0ull;  // dummy 0: never selected
  }
  __shared__ int hist[256];
  __shared__ int wtot[4];
  __shared__ int sbin, sneed;
  unsigned long long prefix = 0;
  int need = NPOS;  // 1-indexed rank of the boundary element
  const int lane = t & 63;
#pragma unroll
  for (int p = 0; p < 6; ++p) {
    const int shift = 40 - 8 * p;
    hist[t] = 0;
    __syncthreads();                               // zeros visible
    if (p == 0) {
      // all keys (incl. dummies) match the empty prefix; count by distinct
      // digit per wave: ballot + 1 atomic per digit value (~4 iterations).
#pragma unroll
      for (int j = 0; j < 8; ++j) {
        unsigned d = (unsigned)((k[j] >> 40) & 255);
        unsigned long long rem = ~0ull;            // wave-uniform loop
        while (rem) {
          int leader = __builtin_ctzll(rem);
          unsigned dl = (unsigned)__shfl((int)d, leader, 64);
          unsigned long long m = __ballot(d == dl);
          if (lane == leader)
            atomicAdd(&hist[dl], (int)__builtin_popcountll(m));
          rem &= ~m;
        }
      }
    } else {
      const unsigned long long hmask = ~((1ull << (shift + 8)) - 1);
#pragma unroll
      for (int j = 0; j < 8; ++j) {
        if ((k[j] & hmask) == prefix)
          atomicAdd(&hist[(int)((k[j] >> shift) & 255)], 1);
      }
    }
    __syncthreads();                               // histogram complete
    int v = hist[t];
    int S = v;                                     // suffix sum within wave's 64 bins
#pragma unroll
    for (int off = 1; off < 64; off <<= 1) {
      int u = __shfl_down(S, off, 64);
      if (lane + off < 64) S += u;
    }
    if (lane == 0) wtot[t >> 6] = S;               // wave total
    __syncthreads();                               // wtot visible
    int w = t >> 6;
#pragma unroll
    for (int w2 = 1; w2 < 4; ++w2)
      if (w2 > w) S += wtot[w2];
    // unique crossing: S[t] >= need > S[t+1]  (S nonincreasing, S[0] >= need)
    if (S >= need && (S - v) < need) { sbin = t; sneed = need - (S - v); }
    __syncthreads();                               // sbin/sneed visible
    prefix |= ((unsigned long long)sbin) << shift;
    need = sneed;
  }
  const unsigned long long k64 = prefix;  // exact key of the 64th largest
#pragma unroll
  for (int j = 0; j < 8; ++j) {
    int i = t + j * 256;
    if (i < NROI) {
      int ridx = b * NROI + i;
      int v = 0;
      if (k[j] >= k64) v = klab[ridx] + 1;  // positive roi: class+1
      pc[ridx] = v;
    }
  }
}

// K3: coalesced nontemporal float4 writer of both outputs — now a pure
// streaming pass: per delta row, read the 4B class code (L2-resident, 256 KB
// footprint, 21-way reuse) and the precomputed delta only on the 1-in-21 hit.
// Negative rois: pc = 0 -> every delta row zero, label one-hot at class 0 —
// same semantics as the reference's zeroed expanded_gt_boxes/labels.
//   out[0 .. 1343999]       : delta rows, one float4 per (b, roi, cls)
//   out[1344000 .. 1679999] : labels, 4 consecutive fp32 per float4
__global__ __launch_bounds__(256) void write_out_kernel(
    const int* __restrict__ pc, const float4* __restrict__ delta,
    float4* __restrict__ out) {
  const int ND4 = BATCH * NROI * NLBL;        // 1,344,000 delta float4 rows
  const int NL4 = (BATCH * NROI * NLBL) / 4;  //   336,000 label float4s
  int i = blockIdx.x * 256 + threadIdx.x;
  if (i < ND4) {
    int b = i / (NROI * NLBL);
    int rem = i - b * (NROI * NLBL);
    int r = rem / NLBL;
    int cls = rem - r * NLBL;
    int p = pc[b * NROI + r];
    float4 v = make_float4(0.f, 0.f, 0.f, 0.f);
    if (cls + 1 == p) v = delta[b * NROI + r];
    nt_store(v, &out[i]);
  } else if (i < ND4 + NL4) {
    int i2 = i - ND4;
    int e = i2 * 4;
    float v[4];
#pragma unroll
    for (int kk = 0; kk < 4; ++kk) {
      int ei = e + kk;
      int b = ei / (NROI * NLBL);
      int rem = ei - b * (NROI * NLBL);
      int r = rem / NLBL;
      int cls = rem - r * NLBL;
      int p = pc[b * NROI + r];
      int lc = (p != 0) ? (p - 1) : 0;
      v[kk] = (cls == lc) ? 1.0f : 0.0f;
    }
    float4 vv = make_float4(v[0], v[1], v[2], v[3]);
    nt_store(vv, &out[i]);
  }
}

extern "C" void kernel_launch(void* const* d_in, const int* in_sizes, int n_in,
                              void* d_out, int out_size, void* d_ws, size_t ws_size,
                              hipStream_t stream) {
  const float* roi = (const float*)d_in[0];  // (32,2000,4) fp32
  const float* gt  = (const float*)d_in[1];  // (32,100,4)  fp32
  const int* gtlab = (const int*)d_in[2];    // (32,100)    int32

  // workspace layout (bytes):
  //   [0,512000)             keys   u64[64000]
  //   [512000,1536000)       delta  float4[64000] (16B aligned: 512000%16==0)
  //   [1536000,1792000)      klab   i32[64000]   (gtlab of argmax gt)
  //   [1792000,2048000)      pc     i32[64000]   (pos ? label+1 : 0)
  char* ws = (char*)d_ws;
  unsigned long long* keys = (unsigned long long*)ws;
  float4* delta = (float4*)(ws + 512000);
  int*    klab  = (int*)(ws + 1536000);
  int*    pc    = (int*)(ws + 1792000);

  iou_max_kernel<<<dim3(8, BATCH), 256, 0, stream>>>(
      (const float4*)roi, (const float4*)gt, gtlab, keys, delta, klab);
  select_kernel<<<dim3(BATCH), 256, 0, stream>>>(keys, klab, pc);
  const int total4 = BATCH * NROI * NLBL + (BATCH * NROI * NLBL) / 4;  // 1,680,000
  write_out_kernel<<<dim3((total4 + 255) / 256), 256, 0, stream>>>(
      pc, delta, (float4*)d_out);
}